// Round 2
// baseline (720.431 us; speedup 1.0000x reference)
//
#include <hip/hip_runtime.h>
#include <math.h>

#define BATCH 4
#define NTOK  16384
#define CDIM  512
#define NH    8
#define HD    64
#define M_ROWS (BATCH*NTOK)
#define KDIM  512

typedef _Float16 f16;
typedef _Float16 f16x8 __attribute__((ext_vector_type(8)));
typedef _Float16 f16x4 __attribute__((ext_vector_type(4)));
typedef _Float16 f16x2 __attribute__((ext_vector_type(2)));
typedef float    f32x4 __attribute__((ext_vector_type(4)));

__device__ __forceinline__ void load_lds16(const void* g, void* l) {
    __builtin_amdgcn_global_load_lds(
        (const __attribute__((address_space(1))) void*)g,
        (__attribute__((address_space(3))) void*)l, 16, 0, 0);
}

__global__ void rope_tables(float* __restrict__ tab) {
    int tid = threadIdx.x;
    for (int i = 0; i < 32; i++) {
        int idx = tid + i * 256;
        int grp = idx >> 11;
        int rem = idx & 2047;
        int t   = rem >> 4;
        int fi  = rem & 15;
        float freq_f = (float)pow(10.0, -(double)fi / 16.0);
        double ang = (double)t * (double)freq_f;
        tab[idx] = (float)((grp & 1) ? sin(ang) : cos(ang));
    }
}

__global__ void convert_x_f16(const float* __restrict__ in, f16* __restrict__ outp) {
    int i = blockIdx.x * 256 + threadIdx.x;
    float4 a = *(const float4*)&in[(size_t)i * 8];
    float4 b = *(const float4*)&in[(size_t)i * 8 + 4];
    f16x8 o;
    o[0]=(f16)a.x; o[1]=(f16)a.y; o[2]=(f16)a.z; o[3]=(f16)a.w;
    o[4]=(f16)b.x; o[5]=(f16)b.y; o[6]=(f16)b.z; o[7]=(f16)b.w;
    *(f16x8*)&outp[(size_t)i * 8] = o;
}

__global__ void convert_wT(const float* __restrict__ w, f16* __restrict__ wt, int N) {
    int idx = blockIdx.x * 256 + threadIdx.x;
    int n = idx >> 9, k = idx & 511;
    wt[idx] = (f16)w[(size_t)k * N + n];
}

// ---------------- fp16 MFMA GEMM, 128x128 tile, BK=64, 2-phase pipeline -----
// T3 minimum 2-phase: double-buffered LDS; per K-step issue stage(t+1) BEFORE
// ds_read+MFMA of tile t, then a single __syncthreads() (its implicit
// vmcnt(0) drain lands AFTER 32 MFMAs of cover instead of before them).
// LDS tiles [128][64] f16, T2 XOR-swizzle (chunk ^= row&7) applied on both
// the pre-swizzled global source and the ds_read side (rule 21). Conflicts
// measured 0. XCD-swizzled 1D grid for L2 locality.
template<int MODE>
__global__ __launch_bounds__(256, 2)
void gemm_f16(const f16* __restrict__ A, const f16* __restrict__ Bt,
              const float* __restrict__ bias,
              float* __restrict__ Co,
              f16* __restrict__ qd, f16* __restrict__ kd, f16* __restrict__ vd,
              const float* __restrict__ tab, int ncol_tiles)
{
    __shared__ f16 As[2][128 * 64];
    __shared__ f16 Bs[2][128 * 64];
    const int tid  = threadIdx.x;
    const int lane = tid & 63;
    const int wave = tid >> 6;
    const int wy = wave >> 1, wx = wave & 1;

    const int bid = blockIdx.x;
    const int xcd = bid & 7;
    const int idx = bid >> 3;
    const int ct  = idx % ncol_tiles;
    const int rt  = (idx / ncol_tiles) * 8 + xcd;
    const int row0 = rt * 128;
    const int col0 = ct * 128;

    const int l15 = lane & 15;
    const int l4  = lane >> 4;

    f32x4 acc[4][4];
    #pragma unroll
    for (int mt = 0; mt < 4; mt++)
        #pragma unroll
        for (int nt = 0; nt < 4; nt++)
            acc[mt][nt] = (f32x4){0.f, 0.f, 0.f, 0.f};

    const int pbase = wave * 256;   // 16B-chunk base for this wave (4 issues x 64)

    // stage BK=64 tile at k0 into buffer buf (linear LDS dest, swizzled source)
    auto stage = [&](int buf, int k0) {
        #pragma unroll
        for (int i = 0; i < 4; i++) {
            int p  = pbase + i * 64 + lane;   // chunk id 0..1023
            int m  = p >> 3;                  // tile row 0..127
            int jp = p & 7;                   // physical 16B chunk within row
            int j  = jp ^ (m & 7);            // logical k-chunk to fetch (swizzle)
            load_lds16(&A [(size_t)(row0 + m) * KDIM + k0 + j * 8],
                       &As[buf][(pbase + i * 64) * 8]);
            load_lds16(&Bt[(size_t)(col0 + m) * KDIM + k0 + j * 8],
                       &Bs[buf][(pbase + i * 64) * 8]);
        }
    };

    auto compute = [&](int buf) {
        #pragma unroll
        for (int s = 0; s < 2; s++) {
            f16x8 af[4], bf[4];
            #pragma unroll
            for (int t = 0; t < 4; t++) {
                int ra = wy * 64 + t * 16 + l15;
                int rb = wx * 64 + t * 16 + l15;
                int ca = ((s << 2) | l4) ^ (ra & 7);
                int cb = ((s << 2) | l4) ^ (rb & 7);
                af[t] = *(const f16x8*)&As[buf][ra * 64 + ca * 8];
                bf[t] = *(const f16x8*)&Bs[buf][rb * 64 + cb * 8];
            }
            #pragma unroll
            for (int mt = 0; mt < 4; mt++)
                #pragma unroll
                for (int nt = 0; nt < 4; nt++)
                    acc[mt][nt] = __builtin_amdgcn_mfma_f32_16x16x32_f16(af[mt], bf[nt], acc[mt][nt], 0, 0, 0);
        }
    };

    stage(0, 0);
    __syncthreads();
    #pragma unroll
    for (int st = 1; st < KDIM / 64; ++st) {
        stage(st & 1, st * 64);          // prefetch next tile (other buffer)
        compute((st - 1) & 1);           // MFMA current tile
        __syncthreads();                 // single drain per K-step, after compute
    }
    compute((KDIM / 64 - 1) & 1);

    if (MODE == 0) {
        // LDS-transpose epilogue: 4 steps of 32 rows x 128 cols fp32 (16 KB,
        // aliases As), flushed as fully-coalesced float4 stores.
        __syncthreads();                 // other waves may still read As/Bs
        float* ep = (float*)&As[0][0];   // 32*128 floats
        #pragma unroll
        for (int mt = 0; mt < 4; mt++) {
            #pragma unroll
            for (int nt = 0; nt < 4; nt++) {
                int col = wx * 64 + nt * 16 + l15;
                float bv = bias[col0 + col];
                #pragma unroll
                for (int r = 0; r < 4; r++) {
                    int rp = wy * 16 + l4 * 4 + r;  // 0..31
                    ep[rp * 128 + col] = acc[mt][nt][r] + bv;
                }
            }
            __syncthreads();
            #pragma unroll
            for (int j = 0; j < 4; j++) {
                int id = tid + j * 256;             // 0..1023 float4s
                int rp = id >> 5, c4 = id & 31;
                int grow = row0 + (rp >> 4) * 64 + mt * 16 + (rp & 15);
                float4 v4 = *(const float4*)&ep[rp * 128 + c4 * 4];
                *(float4*)&Co[(size_t)grow * CDIM + col0 + c4 * 4] = v4;
            }
            __syncthreads();
        }
    } else {
        const int which = col0 >> 9;
        f16* dst = (which == 0) ? qd : (which == 1) ? kd : vd;
        #pragma unroll
        for (int nt = 0; nt < 4; nt++) {
            int coln = col0 + wx * 64 + nt * 16 + l15;
            int c512 = coln & 511;
            float bv = bias[coln];
            if (which == 2) {
                #pragma unroll
                for (int mt = 0; mt < 4; mt++)
                    #pragma unroll
                    for (int r = 0; r < 4; r++) {
                        int row = row0 + wy * 64 + mt * 16 + l4 * 4 + r;
                        float val = acc[mt][nt][r] + bv;
                        float pv  = __shfl_xor(val, 1, 64);
                        if (!(lane & 1)) {
                            f16x2 pk; pk[0] = (f16)val; pk[1] = (f16)pv;
                            *(f16x2*)&dst[(size_t)row * CDIM + c512] = pk;
                        }
                    }
            } else {
                int ch  = c512 & 63;
                int isy = ch >> 5;
                int fid = (ch & 31) >> 1;
                const float* ctb = tab + (isy ? 4096 : 0)    + fid;
                const float* stb = tab + (isy ? 6144 : 2048) + fid;
                #pragma unroll
                for (int mt = 0; mt < 4; mt++)
                    #pragma unroll
                    for (int r = 0; r < 4; r++) {
                        int row = row0 + wy * 64 + mt * 16 + l4 * 4 + r;
                        int tok = row & (NTOK - 1);
                        int t   = isy ? (tok >> 7) : (tok & 127);
                        float c = ctb[t * 16], s = stb[t * 16];
                        float val = acc[mt][nt][r] + bv;
                        float pv  = __shfl_xor(val, 1, 64);
                        float xr = (lane & 1) ? pv  : val;
                        float xi = (lane & 1) ? val : pv;
                        float o_r = xr * c - xi * s;
                        float o_i = xr * s + xi * c;
                        o_r = (o_r > 0.f) ? o_r + 1.f : __expf(o_r);
                        o_i = (o_i > 0.f) ? o_i + 1.f : __expf(o_i);
                        if (!(lane & 1)) {
                            f16x2 pk; pk[0] = (f16)o_r; pk[1] = (f16)o_i;
                            *(f16x2*)&dst[(size_t)row * CDIM + c512] = pk;
                        }
                    }
            }
        }
    }
}

__global__ __launch_bounds__(256, 4)
void kv_kernel(const f16* __restrict__ kk, const f16* __restrict__ vv,
               float* __restrict__ kv, float* __restrict__ ksum)
{
    int bh = blockIdx.x;
    int b = bh >> 3, h = bh & 7;
    int t0 = blockIdx.y * 1024;
    __shared__ float ks[64][68];
    __shared__ float vs[64][68];
    int tid = threadIdx.x;
    int tx = tid & 15;
    int ty = tid >> 4;
    float acc[4][4];
    float ksacc[4];
    #pragma unroll
    for (int r = 0; r < 4; r++) { ksacc[r] = 0.f;
        #pragma unroll
        for (int j = 0; j < 4; j++) acc[r][j] = 0.f; }

    const size_t rowbase = (size_t)b * NTOK;
    for (int tt = t0; tt < t0 + 1024; tt += 64) {
        #pragma unroll
        for (int i = 0; i < 2; i++) {
            int idx = tid + i * 256;
            int tok = idx >> 3;
            int o   = (idx & 7) * 8;
            size_t g = (rowbase + tt + tok) * CDIM + h * HD + o;
            f16x8 k8 = *(const f16x8*)&kk[g];
            f16x8 v8 = *(const f16x8*)&vv[g];
            float4 klo = {(float)k8[0], (float)k8[1], (float)k8[2], (float)k8[3]};
            float4 khi = {(float)k8[4], (float)k8[5], (float)k8[6], (float)k8[7]};
            float4 vlo = {(float)v8[0], (float)v8[1], (float)v8[2], (float)v8[3]};
            float4 vhi = {(float)v8[4], (float)v8[5], (float)v8[6], (float)v8[7]};
            *(float4*)&ks[tok][o]     = klo;
            *(float4*)&ks[tok][o + 4] = khi;
            *(float4*)&vs[tok][o]     = vlo;
            *(float4*)&vs[tok][o + 4] = vhi;
        }
        __syncthreads();
        #pragma unroll 8
        for (int t = 0; t < 64; t++) {
            float4 kd4 = *(const float4*)&ks[t][ty * 4];
            float4 vd4 = *(const float4*)&vs[t][tx * 4];
            float ka[4] = {kd4.x, kd4.y, kd4.z, kd4.w};
            float va[4] = {vd4.x, vd4.y, vd4.z, vd4.w};
            #pragma unroll
            for (int r = 0; r < 4; r++) {
                ksacc[r] += ka[r];
                #pragma unroll
                for (int j = 0; j < 4; j++) acc[r][j] += ka[r] * va[j];
            }
        }
        __syncthreads();
    }
    #pragma unroll
    for (int r = 0; r < 4; r++)
        #pragma unroll
        for (int j = 0; j < 4; j++)
            atomicAdd(&kv[bh * 4096 + (ty * 4 + r) * 64 + tx * 4 + j], acc[r][j]);
    if (tx == 0) {
        #pragma unroll
        for (int r = 0; r < 4; r++) atomicAdd(&ksum[bh * 64 + ty * 4 + r], ksacc[r]);
    }
}

__global__ __launch_bounds__(256, 4)
void attn_kernel(const f16* __restrict__ q, const float* __restrict__ kv,
                 const float* __restrict__ ksum, f16* __restrict__ attnh)
{
    int bh = blockIdx.x;
    int b = bh >> 3, h = bh & 7;
    int rc = blockIdx.y;
    __shared__ float kvs[64][68];
    __shared__ float qs[64][68];
    __shared__ float ksums[64];
    __shared__ float zpart[64][4];
    __shared__ float zs[64];
    int tid = threadIdx.x;
    int tx = tid & 15;
    int ty = tid >> 4;

    #pragma unroll
    for (int i = 0; i < 4; i++) {
        int idx = tid + i * 256;
        *(float4*)&kvs[idx >> 4][(idx & 15) * 4] = *(const float4*)&kv[bh * 4096 + idx * 4];
    }
    if (tid < 64) ksums[tid] = ksum[bh * 64 + tid];

    for (int sub = 0; sub < 4; sub++) {
        int r0 = rc * 256 + sub * 64;
        #pragma unroll
        for (int i = 0; i < 2; i++) {
            int idx = tid + i * 256;
            int rr = idx >> 3;
            int o  = (idx & 7) * 8;
            f16x8 q8 = *(const f16x8*)&q[((size_t)b * NTOK + r0 + rr) * CDIM + h * HD + o];
            float4 lo = {(float)q8[0], (float)q8[1], (float)q8[2], (float)q8[3]};
            float4 hi = {(float)q8[4], (float)q8[5], (float)q8[6], (float)q8[7]};
            *(float4*)&qs[rr][o]     = lo;
            *(float4*)&qs[rr][o + 4] = hi;
        }
        __syncthreads();
        {
            int row = tid & 63, g = tid >> 6;
            float p = 0.f;
            #pragma unroll
            for (int d = 0; d < 16; d++) p += qs[row][g * 16 + d] * ksums[g * 16 + d];
            zpart[row][g] = p;
        }
        __syncthreads();
        if (tid < 64)
            zs[tid] = 1.f / (zpart[tid][0] + zpart[tid][1] + zpart[tid][2] + zpart[tid][3] + 1e-6f);
        __syncthreads();

        float acc[4][4];
        #pragma unroll
        for (int r = 0; r < 4; r++)
            #pragma unroll
            for (int e = 0; e < 4; e++) acc[r][e] = 0.f;

        for (int d = 0; d < 64; d += 4) {
            float qa[4][4], ka[4][4];
            #pragma unroll
            for (int r = 0; r < 4; r++) {
                float4 v4 = *(const float4*)&qs[ty * 4 + r][d];
                qa[r][0]=v4.x; qa[r][1]=v4.y; qa[r][2]=v4.z; qa[r][3]=v4.w;
            }
            #pragma unroll
            for (int j = 0; j < 4; j++) {
                float4 v4 = *(const float4*)&kvs[d + j][tx * 4];
                ka[j][0]=v4.x; ka[j][1]=v4.y; ka[j][2]=v4.z; ka[j][3]=v4.w;
            }
            #pragma unroll
            for (int r = 0; r < 4; r++)
                #pragma unroll
                for (int j = 0; j < 4; j++)
                    #pragma unroll
                    for (int e = 0; e < 4; e++)
                        acc[r][e] += qa[r][j] * ka[j][e];
        }
        #pragma unroll
        for (int r = 0; r < 4; r++) {
            float z = zs[ty * 4 + r];
            f16x4 o4;
            o4[0] = (f16)(acc[r][0] * z); o4[1] = (f16)(acc[r][1] * z);
            o4[2] = (f16)(acc[r][2] * z); o4[3] = (f16)(acc[r][3] * z);
            *(f16x4*)&attnh[((size_t)b * NTOK + r0 + ty * 4 + r) * CDIM + h * HD + tx * 4] = o4;
        }
        __syncthreads();
    }
}

extern "C" void kernel_launch(void* const* d_in, const int* in_sizes, int n_in,
                              void* d_out, int out_size, void* d_ws, size_t ws_size,
                              hipStream_t stream)
{
    const float* x      = (const float*)d_in[0];
    const float* w_qkv  = (const float*)d_in[1];
    const float* b_qkv  = (const float*)d_in[2];
    const float* w_proj = (const float*)d_in[3];
    const float* b_proj = (const float*)d_in[4];
    float* out = (float*)d_out;
    char*  ws  = (char*)d_ws;

    const size_t NCB = (size_t)M_ROWS * CDIM * sizeof(f16);   // 64 MiB
    f16*   xh   = (f16*)(ws);
    f16*   qh   = (f16*)(ws + NCB * 1);
    f16*   kh   = (f16*)(ws + NCB * 2);
    f16*   vh   = (f16*)(ws + NCB * 3);          // reused as attn_h after kv_kernel
    f16*   wqt  = (f16*)(ws + NCB * 4);
    f16*   wpt  = (f16*)(ws + NCB * 4 + (1536 * 512) * sizeof(f16));
    float* tab  = (float*)(ws + NCB * 4 + (1536 * 512 + 512 * 512) * sizeof(f16));
    float* kvp  = tab + 8192;
    float* ksum = kvp + 32 * 4096;

    hipMemsetAsync(kvp, 0, (32 * 4096 + 32 * 64) * sizeof(float), stream);
    rope_tables<<<1, 256, 0, stream>>>(tab);
    convert_x_f16<<<M_ROWS * CDIM / 8 / 256, 256, 0, stream>>>(x, xh);
    convert_wT<<<1536 * 512 / 256, 256, 0, stream>>>(w_qkv, wqt, 1536);
    convert_wT<<<512 * 512 / 256, 256, 0, stream>>>(w_proj, wpt, 512);

    gemm_f16<1><<<6144, 256, 0, stream>>>(xh, wqt, b_qkv,
                                          nullptr, qh, kh, vh, tab, 12);
    kv_kernel<<<dim3(32, 16), 256, 0, stream>>>(kh, vh, kvp, ksum);
    attn_kernel<<<dim3(32, 64), 256, 0, stream>>>(qh, kvp, ksum, vh);
    gemm_f16<0><<<2048, 256, 0, stream>>>(vh, wpt, b_proj,
                                          out, nullptr, nullptr, nullptr, nullptr, 4);
}

// Round 3
// 548.561 us; speedup vs baseline: 1.3133x; 1.3133x over previous
//
#include <hip/hip_runtime.h>
#include <math.h>

#define BATCH 4
#define NTOK  16384
#define CDIM  512
#define NH    8
#define HD    64
#define M_ROWS (BATCH*NTOK)
#define KDIM  512

typedef _Float16 f16;
typedef _Float16 f16x8 __attribute__((ext_vector_type(8)));
typedef _Float16 f16x4 __attribute__((ext_vector_type(4)));
typedef _Float16 f16x2 __attribute__((ext_vector_type(2)));
typedef float    f32x4 __attribute__((ext_vector_type(4)));

__device__ __forceinline__ void load_lds16(const void* g, void* l) {
    __builtin_amdgcn_global_load_lds(
        (const __attribute__((address_space(1))) void*)g,
        (__attribute__((address_space(3))) void*)l, 16, 0, 0);
}

// tab = float2[2][128][16]: {cos,sin} for isy in {x:t=tok&127, y:t=tok>>7},
// freq index fi (16 freqs, 10^{-fi/16}).
__global__ void rope_tables(float* __restrict__ tab) {
    int tid = threadIdx.x;
    for (int i = 0; i < 16; i++) {
        int idx = tid + i * 256;          // 0..4095 pairs
        int t   = (idx >> 4) & 127;
        int fi  = idx & 15;
        double freq = pow(10.0, -(double)fi / 16.0);
        double ang  = (double)t * freq;
        tab[idx * 2]     = (float)cos(ang);
        tab[idx * 2 + 1] = (float)sin(ang);
    }
}

__global__ void convert_x_f16(const float* __restrict__ in, f16* __restrict__ outp) {
    int i = blockIdx.x * 256 + threadIdx.x;
    float4 a = *(const float4*)&in[(size_t)i * 8];
    float4 b = *(const float4*)&in[(size_t)i * 8 + 4];
    f16x8 o;
    o[0]=(f16)a.x; o[1]=(f16)a.y; o[2]=(f16)a.z; o[3]=(f16)a.w;
    o[4]=(f16)b.x; o[5]=(f16)b.y; o[6]=(f16)b.z; o[7]=(f16)b.w;
    *(f16x8*)&outp[(size_t)i * 8] = o;
}

// PERM=1: within every 32-col block, position p<16 holds true col 2p,
// p>=16 holds 2(p-16)+1 — puts RoPE pair (2f,2f+1) in the SAME lane at
// adjacent nt tiles of the GEMM epilogue (no shfl, paired f16x2 store).
template<int PERM>
__global__ void convert_wT(const float* __restrict__ w, f16* __restrict__ wt, int N) {
    int idx = blockIdx.x * 256 + threadIdx.x;
    int n = idx >> 9, k = idx & 511;
    int tc = n;
    if (PERM) {
        int blk = n >> 5, pos = n & 31;
        tc = blk * 32 + ((pos < 16) ? (pos * 2) : ((pos - 16) * 2 + 1));
    }
    wt[idx] = (f16)w[(size_t)k * N + tc];
}

// ---------------- fp16 MFMA GEMM, 128x128 tile, BK=64 per barrier ------------
// Round-1 proven structure: single-buffered LDS [128][64] f16, T2 XOR-swizzle
// (chunk ^= row&7) on both the pre-swizzled global source and the ds_read
// side (rule 21; conflicts measured 0). 32 KB LDS -> ~3 blocks/CU whose
// cross-block overlap hides the stage drain (m114; explicit dbuf regressed).
// XCD-swizzled 1D grid for L2 locality.
template<int MODE>
__global__ __launch_bounds__(256, 2)
void gemm_f16(const f16* __restrict__ A, const f16* __restrict__ Bt,
              const float* __restrict__ bias,
              float* __restrict__ Co,
              f16* __restrict__ qd, f16* __restrict__ kd, f16* __restrict__ vd,
              const float* __restrict__ tab, int ncol_tiles)
{
    __shared__ f16 As[128 * 64];
    __shared__ f16 Bs[128 * 64];
    const int tid  = threadIdx.x;
    const int lane = tid & 63;
    const int wave = tid >> 6;
    const int wy = wave >> 1, wx = wave & 1;

    const int bid = blockIdx.x;
    const int xcd = bid & 7;
    const int idx = bid >> 3;
    const int ct  = idx % ncol_tiles;
    const int rt  = (idx / ncol_tiles) * 8 + xcd;
    const int row0 = rt * 128;
    const int col0 = ct * 128;

    const int l15 = lane & 15;
    const int l4  = lane >> 4;

    f32x4 acc[4][4];
    #pragma unroll
    for (int mt = 0; mt < 4; mt++)
        #pragma unroll
        for (int nt = 0; nt < 4; nt++)
            acc[mt][nt] = (f32x4){0.f, 0.f, 0.f, 0.f};

    const int pbase = wave * 256;   // 16B-chunk base for this wave (4 issues x 64)

    for (int k0 = 0; k0 < KDIM; k0 += 64) {
        #pragma unroll
        for (int i = 0; i < 4; i++) {
            int p  = pbase + i * 64 + lane;   // chunk id 0..1023
            int m  = p >> 3;                  // tile row 0..127
            int jp = p & 7;                   // physical 16B chunk within row
            int j  = jp ^ (m & 7);            // logical k-chunk to fetch (swizzle)
            load_lds16(&A [(size_t)(row0 + m) * KDIM + k0 + j * 8],
                       &As[(pbase + i * 64) * 8]);
            load_lds16(&Bt[(size_t)(col0 + m) * KDIM + k0 + j * 8],
                       &Bs[(pbase + i * 64) * 8]);
        }
        __syncthreads();

        #pragma unroll
        for (int s = 0; s < 2; s++) {
            f16x8 af[4], bf[4];
            #pragma unroll
            for (int t = 0; t < 4; t++) {
                int ra = wy * 64 + t * 16 + l15;
                int rb = wx * 64 + t * 16 + l15;
                int ca = ((s << 2) | l4) ^ (ra & 7);
                int cb = ((s << 2) | l4) ^ (rb & 7);
                af[t] = *(const f16x8*)&As[ra * 64 + ca * 8];
                bf[t] = *(const f16x8*)&Bs[rb * 64 + cb * 8];
            }
            #pragma unroll
            for (int mt = 0; mt < 4; mt++)
                #pragma unroll
                for (int nt = 0; nt < 4; nt++)
                    acc[mt][nt] = __builtin_amdgcn_mfma_f32_16x16x32_f16(af[mt], bf[nt], acc[mt][nt], 0, 0, 0);
        }
        __syncthreads();
    }

    if (MODE == 0) {
        // LDS-transpose epilogue: 4 steps of 32 rows x 128 cols fp32 (16 KB,
        // aliases As), flushed as fully-coalesced float4 stores.
        float* ep = (float*)&As[0];              // 32*128 floats
        #pragma unroll
        for (int mt = 0; mt < 4; mt++) {
            #pragma unroll
            for (int nt = 0; nt < 4; nt++) {
                int col = wx * 64 + nt * 16 + l15;
                float bv = bias[col0 + col];
                #pragma unroll
                for (int r = 0; r < 4; r++) {
                    int rp = wy * 16 + l4 * 4 + r;  // 0..31
                    ep[rp * 128 + col] = acc[mt][nt][r] + bv;
                }
            }
            __syncthreads();
            #pragma unroll
            for (int j = 0; j < 4; j++) {
                int id = tid + j * 256;             // 0..1023 float4s
                int rp = id >> 5, c4 = id & 31;
                int grow = row0 + (rp >> 4) * 64 + mt * 16 + (rp & 15);
                float4 v4 = *(const float4*)&ep[rp * 128 + c4 * 4];
                *(float4*)&Co[(size_t)grow * CDIM + col0 + c4 * 4] = v4;
            }
            __syncthreads();
        }
    } else {
        // Permuted-column epilogue: lane l15 owns true cols (2*l15, 2*l15+1)
        // of 32-block B32 via acc[mt][2q] / acc[mt][2q+1]. Full-wave f16x2
        // stores (64B contiguous per l4 row-group), one float2 table load.
        const int which = col0 >> 9;
        f16* dst = (which == 0) ? qd : (which == 1) ? kd : vd;
        const float2* tab2 = (const float2*)tab;
        #pragma unroll
        for (int q = 0; q < 2; q++) {
            int B32  = (col0 + wx * 64 + q * 32) >> 5;   // 32-col block id
            int t0   = B32 * 32 + 2 * l15;               // true col (even)
            int c512 = t0 & 511;
            float bv0 = bias[t0];
            float bv1 = bias[t0 + 1];
            int isy  = B32 & 1;                          // x-half / y-half of head
            const float2* ct = tab2 + isy * 2048 + l15;  // [isy][t][fi=l15]
            if (which == 2) {
                #pragma unroll
                for (int mt = 0; mt < 4; mt++)
                    #pragma unroll
                    for (int r = 0; r < 4; r++) {
                        int row = row0 + wy * 64 + mt * 16 + l4 * 4 + r;
                        f16x2 pk;
                        pk[0] = (f16)(acc[mt][2 * q][r]     + bv0);
                        pk[1] = (f16)(acc[mt][2 * q + 1][r] + bv1);
                        *(f16x2*)&dst[(size_t)row * CDIM + c512] = pk;
                    }
            } else {
                #pragma unroll
                for (int mt = 0; mt < 4; mt++)
                    #pragma unroll
                    for (int r = 0; r < 4; r++) {
                        int row = row0 + wy * 64 + mt * 16 + l4 * 4 + r;
                        int tok = row & (NTOK - 1);
                        int t   = isy ? (tok >> 7) : (tok & 127);
                        float2 cs = ct[t * 16];
                        float xr = acc[mt][2 * q][r]     + bv0;
                        float xi = acc[mt][2 * q + 1][r] + bv1;
                        float o_r = xr * cs.x - xi * cs.y;
                        float o_i = xr * cs.y + xi * cs.x;
                        o_r = (o_r > 0.f) ? o_r + 1.f : __expf(o_r);
                        o_i = (o_i > 0.f) ? o_i + 1.f : __expf(o_i);
                        f16x2 pk; pk[0] = (f16)o_r; pk[1] = (f16)o_i;
                        *(f16x2*)&dst[(size_t)row * CDIM + c512] = pk;
                    }
            }
        }
    }
}

// kv_kernel: unchanged scalar outer-product, but now writes KV TRANSPOSED
// (kvt[e][d]) so attn's MFMA B-fragments read contiguous f16x8 rows.
__global__ __launch_bounds__(256, 4)
void kv_kernel(const f16* __restrict__ kk, const f16* __restrict__ vv,
               float* __restrict__ kvt, float* __restrict__ ksum)
{
    int bh = blockIdx.x;
    int b = bh >> 3, h = bh & 7;
    int t0 = blockIdx.y * 1024;
    __shared__ float ks[64][68];
    __shared__ float vs[64][68];
    int tid = threadIdx.x;
    int tx = tid & 15;
    int ty = tid >> 4;
    float acc[4][4];
    float ksacc[4];
    #pragma unroll
    for (int r = 0; r < 4; r++) { ksacc[r] = 0.f;
        #pragma unroll
        for (int j = 0; j < 4; j++) acc[r][j] = 0.f; }

    const size_t rowbase = (size_t)b * NTOK;
    for (int tt = t0; tt < t0 + 1024; tt += 64) {
        #pragma unroll
        for (int i = 0; i < 2; i++) {
            int idx = tid + i * 256;
            int tok = idx >> 3;
            int o   = (idx & 7) * 8;
            size_t g = (rowbase + tt + tok) * CDIM + h * HD + o;
            f16x8 k8 = *(const f16x8*)&kk[g];
            f16x8 v8 = *(const f16x8*)&vv[g];
            float4 klo = {(float)k8[0], (float)k8[1], (float)k8[2], (float)k8[3]};
            float4 khi = {(float)k8[4], (float)k8[5], (float)k8[6], (float)k8[7]};
            float4 vlo = {(float)v8[0], (float)v8[1], (float)v8[2], (float)v8[3]};
            float4 vhi = {(float)v8[4], (float)v8[5], (float)v8[6], (float)v8[7]};
            *(float4*)&ks[tok][o]     = klo;
            *(float4*)&ks[tok][o + 4] = khi;
            *(float4*)&vs[tok][o]     = vlo;
            *(float4*)&vs[tok][o + 4] = vhi;
        }
        __syncthreads();
        #pragma unroll 8
        for (int t = 0; t < 64; t++) {
            float4 kd4 = *(const float4*)&ks[t][ty * 4];
            float4 vd4 = *(const float4*)&vs[t][tx * 4];
            float ka[4] = {kd4.x, kd4.y, kd4.z, kd4.w};
            float va[4] = {vd4.x, vd4.y, vd4.z, vd4.w};
            #pragma unroll
            for (int r = 0; r < 4; r++) {
                ksacc[r] += ka[r];
                #pragma unroll
                for (int j = 0; j < 4; j++) acc[r][j] += ka[r] * va[j];
            }
        }
        __syncthreads();
    }
    #pragma unroll
    for (int r = 0; r < 4; r++)
        #pragma unroll
        for (int j = 0; j < 4; j++)
            atomicAdd(&kvt[bh * 4096 + (tx * 4 + j) * 64 + (ty * 4 + r)], acc[r][j]);
    if (tx == 0) {
        #pragma unroll
        for (int r = 0; r < 4; r++) atomicAdd(&ksum[bh * 64 + ty * 4 + r], ksacc[r]);
    }
}

// attn via MFMA: out[n][e] = (q[n][:] @ kv[:][e]) / (q[n][:].ksum + eps).
// A-frags straight from global Q (row=l15, k=s*32+l4*8: contiguous f16x8).
// B = KV as split-precision f16 (hi + lo, two MFMAs -> fp32-level accuracy)
// staged once in XOR-swizzled LDS then held in registers across row tiles.
// z computed in-register from the same A-frags (2x shfl_xor reduce).
__global__ __launch_bounds__(256, 4)
void attn_kernel(const f16* __restrict__ q, const float* __restrict__ kvt,
                 const float* __restrict__ ksum, f16* __restrict__ attnh)
{
    int bh = blockIdx.x;
    int b = bh >> 3, h = bh & 7;
    int rc = blockIdx.y;
    __shared__ f16 kvhi[64 * 64];
    __shared__ f16 kvlo[64 * 64];
    int tid = threadIdx.x;
    const int lane = tid & 63;
    const int wave = tid >> 6;
    const int l15 = lane & 15;
    const int l4  = lane >> 4;

    // stage kvT fp32 -> f16 hi/lo, chunk position = chunk ^ (e&7)
    {
        int e = tid >> 2;
        #pragma unroll
        for (int c = 0; c < 2; c++) {
            int chunk = (tid & 3) * 2 + c;
            f16x8 hi8, lo8;
            #pragma unroll
            for (int j = 0; j < 8; j++) {
                float v = kvt[bh * 4096 + e * 64 + chunk * 8 + j];
                f16 hv = (f16)v;
                hi8[j] = hv;
                lo8[j] = (f16)(v - (float)hv);
            }
            int cp = chunk ^ (e & 7);
            *(f16x8*)&kvhi[e * 64 + cp * 8] = hi8;
            *(f16x8*)&kvlo[e * 64 + cp * 8] = lo8;
        }
    }
    // per-lane ksum slice: d = s*32 + l4*8 + j
    float ksA[2][8];
    #pragma unroll
    for (int s = 0; s < 2; s++)
        #pragma unroll
        for (int j = 0; j < 8; j++)
            ksA[s][j] = ksum[bh * 64 + s * 32 + l4 * 8 + j];
    __syncthreads();

    // B fragments to registers, reused for all 4 row tiles
    f16x8 bhi[2][4], blo[2][4];
    #pragma unroll
    for (int s = 0; s < 2; s++)
        #pragma unroll
        for (int nt = 0; nt < 4; nt++) {
            int e  = nt * 16 + l15;
            int cp = ((s << 2) | l4) ^ (e & 7);
            bhi[s][nt] = *(const f16x8*)&kvhi[e * 64 + cp * 8];
            blo[s][nt] = *(const f16x8*)&kvlo[e * 64 + cp * 8];
        }

    const size_t qbase = ((size_t)b * NTOK + rc * 256 + wave * 64) * CDIM + (size_t)h * HD;

    #pragma unroll
    for (int mt = 0; mt < 4; mt++) {
        f16x8 af[2];
        #pragma unroll
        for (int s = 0; s < 2; s++)
            af[s] = *(const f16x8*)&q[qbase + (size_t)(mt * 16 + l15) * CDIM + s * 32 + l4 * 8];

        // z for row n0+l15
        float zp = 0.f;
        #pragma unroll
        for (int s = 0; s < 2; s++)
            #pragma unroll
            for (int j = 0; j < 8; j++)
                zp += (float)af[s][j] * ksA[s][j];
        zp += __shfl_xor(zp, 16, 64);
        zp += __shfl_xor(zp, 32, 64);
        float zinv = 1.f / (zp + 1e-6f);

        f32x4 acc[4];
        #pragma unroll
        for (int nt = 0; nt < 4; nt++) acc[nt] = (f32x4){0.f, 0.f, 0.f, 0.f};
        #pragma unroll
        for (int s = 0; s < 2; s++)
            #pragma unroll
            for (int nt = 0; nt < 4; nt++) {
                acc[nt] = __builtin_amdgcn_mfma_f32_16x16x32_f16(af[s], bhi[s][nt], acc[nt], 0, 0, 0);
                acc[nt] = __builtin_amdgcn_mfma_f32_16x16x32_f16(af[s], blo[s][nt], acc[nt], 0, 0, 0);
            }

        #pragma unroll
        for (int r = 0; r < 4; r++) {
            float zr = __shfl(zinv, l4 * 4 + r, 64);   // z[row l4*4+r] from lane l15==row
            size_t orow = qbase + (size_t)(mt * 16 + l4 * 4 + r) * CDIM;
            #pragma unroll
            for (int nt = 0; nt < 4; nt++)
                attnh[orow + nt * 16 + l15] = (f16)(acc[nt][r] * zr);
        }
    }
}

extern "C" void kernel_launch(void* const* d_in, const int* in_sizes, int n_in,
                              void* d_out, int out_size, void* d_ws, size_t ws_size,
                              hipStream_t stream)
{
    const float* x      = (const float*)d_in[0];
    const float* w_qkv  = (const float*)d_in[1];
    const float* b_qkv  = (const float*)d_in[2];
    const float* w_proj = (const float*)d_in[3];
    const float* b_proj = (const float*)d_in[4];
    float* out = (float*)d_out;
    char*  ws  = (char*)d_ws;

    const size_t NCB = (size_t)M_ROWS * CDIM * sizeof(f16);   // 64 MiB
    f16*   xh   = (f16*)(ws);
    f16*   qh   = (f16*)(ws + NCB * 1);
    f16*   kh   = (f16*)(ws + NCB * 2);
    f16*   vh   = (f16*)(ws + NCB * 3);          // reused as attn_h after kv_kernel
    f16*   wqt  = (f16*)(ws + NCB * 4);
    f16*   wpt  = (f16*)(ws + NCB * 4 + (1536 * 512) * sizeof(f16));
    float* tab  = (float*)(ws + NCB * 4 + (1536 * 512 + 512 * 512) * sizeof(f16));
    float* kvp  = tab + 8192;
    float* ksum = kvp + 32 * 4096;

    hipMemsetAsync(kvp, 0, (32 * 4096 + 32 * 64) * sizeof(float), stream);
    rope_tables<<<1, 256, 0, stream>>>(tab);
    convert_x_f16<<<M_ROWS * CDIM / 8 / 256, 256, 0, stream>>>(x, xh);
    convert_wT<1><<<1536 * 512 / 256, 256, 0, stream>>>(w_qkv, wqt, 1536);
    convert_wT<0><<<512 * 512 / 256, 256, 0, stream>>>(w_proj, wpt, 512);

    gemm_f16<1><<<6144, 256, 0, stream>>>(xh, wqt, b_qkv,
                                          nullptr, qh, kh, vh, tab, 12);
    kv_kernel<<<dim3(32, 16), 256, 0, stream>>>(kh, vh, kvp, ksum);
    attn_kernel<<<dim3(32, 64), 256, 0, stream>>>(qh, kvp, ksum, vh);
    gemm_f16<0><<<2048, 256, 0, stream>>>(vh, wpt, b_proj,
                                          out, nullptr, nullptr, nullptr, nullptr, 4);
}

// Round 5
// 537.907 us; speedup vs baseline: 1.3393x; 1.0198x over previous
//
#include <hip/hip_runtime.h>
#include <math.h>

#define BATCH 4
#define NTOK  16384
#define CDIM  512
#define NH    8
#define HD    64
#define M_ROWS (BATCH*NTOK)
#define KDIM  512

typedef _Float16 f16;
typedef _Float16 f16x8 __attribute__((ext_vector_type(8)));
typedef _Float16 f16x4 __attribute__((ext_vector_type(4)));
typedef _Float16 f16x2 __attribute__((ext_vector_type(2)));
typedef float    f32x4 __attribute__((ext_vector_type(4)));

__device__ __forceinline__ void load_lds16(const void* g, void* l) {
    __builtin_amdgcn_global_load_lds(
        (const __attribute__((address_space(1))) void*)g,
        (__attribute__((address_space(3))) void*)l, 16, 0, 0);
}

// tab = float2[2][128][16]: {cos,sin} for isy in {x:t=tok&127, y:t=tok>>7},
// freq index fi (16 freqs, 10^{-fi/16}).
__global__ void rope_tables(float* __restrict__ tab) {
    int tid = threadIdx.x;
    for (int i = 0; i < 16; i++) {
        int idx = tid + i * 256;          // 0..4095 pairs
        int t   = (idx >> 4) & 127;
        int fi  = idx & 15;
        double freq = pow(10.0, -(double)fi / 16.0);
        double ang  = (double)t * freq;
        tab[idx * 2]     = (float)cos(ang);
        tab[idx * 2 + 1] = (float)sin(ang);
    }
}

__global__ void convert_x_f16(const float* __restrict__ in, f16* __restrict__ outp) {
    int i = blockIdx.x * 256 + threadIdx.x;
    float4 a = *(const float4*)&in[(size_t)i * 8];
    float4 b = *(const float4*)&in[(size_t)i * 8 + 4];
    f16x8 o;
    o[0]=(f16)a.x; o[1]=(f16)a.y; o[2]=(f16)a.z; o[3]=(f16)a.w;
    o[4]=(f16)b.x; o[5]=(f16)b.y; o[6]=(f16)b.z; o[7]=(f16)b.w;
    *(f16x8*)&outp[(size_t)i * 8] = o;
}

// PERM=1: within every 32-col block, position p<16 holds true col 2p,
// p>=16 holds 2(p-16)+1 — puts the col pair (2f,2f+1) in the SAME lane at
// adjacent nt tiles of the GEMM epilogue (no shfl, paired 8B stores).
template<int PERM>
__global__ void convert_wT(const float* __restrict__ w, f16* __restrict__ wt, int N) {
    int idx = blockIdx.x * 256 + threadIdx.x;
    int n = idx >> 9, k = idx & 511;
    int tc = n;
    if (PERM) {
        int blk = n >> 5, pos = n & 31;
        tc = blk * 32 + ((pos < 16) ? (pos * 2) : ((pos - 16) * 2 + 1));
    }
    wt[idx] = (f16)w[(size_t)k * N + tc];
}

// ---------------- fp16 MFMA GEMM, 128x128 tile, BK=64 per barrier ------------
// Proven structure (R3: 144us, MfmaUtil 32%, conflicts 0): single-buffered
// LDS [128][64] f16, T2 XOR-swizzle (chunk ^= row&7) applied on both the
// pre-swizzled global source and the ds_read side (rule 21). 32 KB LDS ->
// ~3 blocks/CU whose cross-block overlap hides the stage drain (explicit
// dbuf regressed: R2). XCD-swizzled 1D grid for L2 locality.
// Both MODE paths use column-PERMUTED weights (convert_wT<1>).
template<int MODE>
__global__ __launch_bounds__(256, 2)
void gemm_f16(const f16* __restrict__ A, const f16* __restrict__ Bt,
              const float* __restrict__ bias,
              float* __restrict__ Co,
              f16* __restrict__ qd, f16* __restrict__ kd, f16* __restrict__ vd,
              const float* __restrict__ tab, int ncol_tiles)
{
    __shared__ f16 As[128 * 64];
    __shared__ f16 Bs[128 * 64];
    const int tid  = threadIdx.x;
    const int lane = tid & 63;
    const int wave = tid >> 6;
    const int wy = wave >> 1, wx = wave & 1;

    const int bid = blockIdx.x;
    const int xcd = bid & 7;
    const int idx = bid >> 3;
    const int ct  = idx % ncol_tiles;
    const int rt  = (idx / ncol_tiles) * 8 + xcd;
    const int row0 = rt * 128;
    const int col0 = ct * 128;

    const int l15 = lane & 15;
    const int l4  = lane >> 4;

    f32x4 acc[4][4];
    #pragma unroll
    for (int mt = 0; mt < 4; mt++)
        #pragma unroll
        for (int nt = 0; nt < 4; nt++)
            acc[mt][nt] = (f32x4){0.f, 0.f, 0.f, 0.f};

    const int pbase = wave * 256;   // 16B-chunk base for this wave (4 issues x 64)

    for (int k0 = 0; k0 < KDIM; k0 += 64) {
        #pragma unroll
        for (int i = 0; i < 4; i++) {
            int p  = pbase + i * 64 + lane;   // chunk id 0..1023
            int m  = p >> 3;                  // tile row 0..127
            int jp = p & 7;                   // physical 16B chunk within row
            int j  = jp ^ (m & 7);            // logical k-chunk to fetch (swizzle)
            load_lds16(&A [(size_t)(row0 + m) * KDIM + k0 + j * 8],
                       &As[(pbase + i * 64) * 8]);
            load_lds16(&Bt[(size_t)(col0 + m) * KDIM + k0 + j * 8],
                       &Bs[(pbase + i * 64) * 8]);
        }
        __syncthreads();

        #pragma unroll
        for (int s = 0; s < 2; s++) {
            f16x8 af[4], bf[4];
            #pragma unroll
            for (int t = 0; t < 4; t++) {
                int ra = wy * 64 + t * 16 + l15;
                int rb = wx * 64 + t * 16 + l15;
                int ca = ((s << 2) | l4) ^ (ra & 7);
                int cb = ((s << 2) | l4) ^ (rb & 7);
                af[t] = *(const f16x8*)&As[ra * 64 + ca * 8];
                bf[t] = *(const f16x8*)&Bs[rb * 64 + cb * 8];
            }
            #pragma unroll
            for (int mt = 0; mt < 4; mt++)
                #pragma unroll
                for (int nt = 0; nt < 4; nt++)
                    acc[mt][nt] = __builtin_amdgcn_mfma_f32_16x16x32_f16(af[mt], bf[nt], acc[mt][nt], 0, 0, 0);
        }
        __syncthreads();
    }

    if (MODE == 0) {
        // Permuted-column direct-store epilogue: lane l15 owns true cols
        // (2*l15, 2*l15+1); float2 stores, 128B contiguous per l4 group.
        // No LDS, no barriers.
        #pragma unroll
        for (int q = 0; q < 2; q++) {
            int B32 = (col0 + wx * 64 + q * 32) >> 5;
            int t0c = B32 * 32 + 2 * l15;
            float bv0 = bias[t0c];
            float bv1 = bias[t0c + 1];
            #pragma unroll
            for (int mt = 0; mt < 4; mt++)
                #pragma unroll
                for (int r = 0; r < 4; r++) {
                    int row = row0 + wy * 64 + mt * 16 + l4 * 4 + r;
                    float2 o2;
                    o2.x = acc[mt][2 * q][r]     + bv0;
                    o2.y = acc[mt][2 * q + 1][r] + bv1;
                    *(float2*)&Co[(size_t)row * CDIM + t0c] = o2;
                }
        }
    } else {
        // Permuted-column epilogue with fused RoPE+ELU for Q/K, plain for V.
        const int which = col0 >> 9;
        f16* dst = (which == 0) ? qd : (which == 1) ? kd : vd;
        const float2* tab2 = (const float2*)tab;
        #pragma unroll
        for (int q = 0; q < 2; q++) {
            int B32  = (col0 + wx * 64 + q * 32) >> 5;   // 32-col block id
            int t0   = B32 * 32 + 2 * l15;               // true col (even)
            int c512 = t0 & 511;
            float bv0 = bias[t0];
            float bv1 = bias[t0 + 1];
            int isy  = B32 & 1;                          // x-half / y-half of head
            const float2* ct = tab2 + isy * 2048 + l15;  // [isy][t][fi=l15]
            if (which == 2) {
                #pragma unroll
                for (int mt = 0; mt < 4; mt++)
                    #pragma unroll
                    for (int r = 0; r < 4; r++) {
                        int row = row0 + wy * 64 + mt * 16 + l4 * 4 + r;
                        f16x2 pk;
                        pk[0] = (f16)(acc[mt][2 * q][r]     + bv0);
                        pk[1] = (f16)(acc[mt][2 * q + 1][r] + bv1);
                        *(f16x2*)&dst[(size_t)row * CDIM + c512] = pk;
                    }
            } else {
                #pragma unroll
                for (int mt = 0; mt < 4; mt++)
                    #pragma unroll
                    for (int r = 0; r < 4; r++) {
                        int row = row0 + wy * 64 + mt * 16 + l4 * 4 + r;
                        int tok = row & (NTOK - 1);
                        int t   = isy ? (tok >> 7) : (tok & 127);
                        float2 cs = ct[t * 16];
                        float xr = acc[mt][2 * q][r]     + bv0;
                        float xi = acc[mt][2 * q + 1][r] + bv1;
                        float o_r = xr * cs.x - xi * cs.y;
                        float o_i = xr * cs.y + xi * cs.x;
                        o_r = (o_r > 0.f) ? o_r + 1.f : __expf(o_r);
                        o_i = (o_i > 0.f) ? o_i + 1.f : __expf(o_i);
                        f16x2 pk; pk[0] = (f16)o_r; pk[1] = (f16)o_i;
                        *(f16x2*)&dst[(size_t)row * CDIM + c512] = pk;
                    }
            }
        }
    }
}

// kv_kernel v2: 8x8 register tiles. Each wave covers 16 of the 64 staged
// tokens with an 8x8 output tile per lane (ly=lane>>3 d-rows, lx=lane&7
// e-cols): 64B LDS per 64 FMA = 2x the arithmetic intensity of the old
// 4x4 layout -> LDS traffic halved (was the bottleneck, ~62us at 69TB/s).
// Wave partials merged once per block through LDS, then 4096 atomics.
// ksum accumulated per-thread during staging (each thread's o-slice is
// fixed since 256 % 8 == 0), reduced via LDS at block end.
__global__ __launch_bounds__(256, 4)
void kv_kernel(const f16* __restrict__ kk, const f16* __restrict__ vv,
               float* __restrict__ kvt, float* __restrict__ ksum)
{
    int bh = blockIdx.x;
    int b = bh >> 3, h = bh & 7;
    int t0 = blockIdx.y * 1024;
    __shared__ float ks[64][68];
    __shared__ float vs[64][68];
    int tid = threadIdx.x;
    const int wave = tid >> 6;
    const int lane = tid & 63;
    const int ly = lane >> 3;
    const int lx = lane & 7;
    const int o  = (tid & 7) * 8;     // fixed dim slice this thread stages

    float acc[8][8];
    float ksacc[8];
    #pragma unroll
    for (int r = 0; r < 8; r++) { ksacc[r] = 0.f;
        #pragma unroll
        for (int j = 0; j < 8; j++) acc[r][j] = 0.f; }

    const size_t rowbase = (size_t)b * NTOK;
    for (int tt = t0; tt < t0 + 1024; tt += 64) {
        #pragma unroll
        for (int i = 0; i < 2; i++) {
            int idx = tid + i * 256;
            int tok = idx >> 3;
            size_t g = (rowbase + tt + tok) * CDIM + h * HD + o;
            f16x8 k8 = *(const f16x8*)&kk[g];
            f16x8 v8 = *(const f16x8*)&vv[g];
            float4 klo = {(float)k8[0], (float)k8[1], (float)k8[2], (float)k8[3]};
            float4 khi = {(float)k8[4], (float)k8[5], (float)k8[6], (float)k8[7]};
            float4 vlo = {(float)v8[0], (float)v8[1], (float)v8[2], (float)v8[3]};
            float4 vhi = {(float)v8[4], (float)v8[5], (float)v8[6], (float)v8[7]};
            *(float4*)&ks[tok][o]     = klo;
            *(float4*)&ks[tok][o + 4] = khi;
            *(float4*)&vs[tok][o]     = vlo;
            *(float4*)&vs[tok][o + 4] = vhi;
            ksacc[0] += klo.x; ksacc[1] += klo.y; ksacc[2] += klo.z; ksacc[3] += klo.w;
            ksacc[4] += khi.x; ksacc[5] += khi.y; ksacc[6] += khi.z; ksacc[7] += khi.w;
        }
        __syncthreads();
        #pragma unroll
        for (int t5 = 0; t5 < 16; t5++) {
            int t = wave * 16 + t5;
            float4 ka0 = *(const float4*)&ks[t][ly * 8];
            float4 ka1 = *(const float4*)&ks[t][ly * 8 + 4];
            float4 va0 = *(const float4*)&vs[t][lx * 8];
            float4 va1 = *(const float4*)&vs[t][lx * 8 + 4];
            float ka[8] = {ka0.x, ka0.y, ka0.z, ka0.w, ka1.x, ka1.y, ka1.z, ka1.w};
            float va[8] = {va0.x, va0.y, va0.z, va0.w, va1.x, va1.y, va1.z, va1.w};
            #pragma unroll
            for (int r = 0; r < 8; r++)
                #pragma unroll
                for (int j = 0; j < 8; j++) acc[r][j] += ka[r] * va[j];
        }
        __syncthreads();
    }

    // ksum partials -> LDS (vs region is free now)
    float* ksl = &vs[0][0];
    {
        float4 a = {ksacc[0], ksacc[1], ksacc[2], ksacc[3]};
        float4 c = {ksacc[4], ksacc[5], ksacc[6], ksacc[7]};
        *(float4*)&ksl[tid * 8]     = a;
        *(float4*)&ksl[tid * 8 + 4] = c;
    }
    // merge 4 wave partials into red[e][d] (transposed), ks region reused
    float* red = &ks[0][0];
    #pragma unroll
    for (int w = 0; w < 4; w++) {
        if (wave == w) {
            #pragma unroll
            for (int j = 0; j < 8; j++) {
                int base = (lx * 8 + j) * 64 + ly * 8;
                float4 lo = {acc[0][j], acc[1][j], acc[2][j], acc[3][j]};
                float4 hi = {acc[4][j], acc[5][j], acc[6][j], acc[7][j]};
                if (w == 0) {
                    *(float4*)&red[base]     = lo;
                    *(float4*)&red[base + 4] = hi;
                } else {
                    float4 p0 = *(const float4*)&red[base];
                    float4 p1 = *(const float4*)&red[base + 4];
                    p0.x += lo.x; p0.y += lo.y; p0.z += lo.z; p0.w += lo.w;
                    p1.x += hi.x; p1.y += hi.y; p1.z += hi.z; p1.w += hi.w;
                    *(float4*)&red[base]     = p0;
                    *(float4*)&red[base + 4] = p1;
                }
            }
        }
        __syncthreads();
    }
    #pragma unroll
    for (int i = 0; i < 16; i++) {
        int idx = tid + i * 256;          // [e][d] order, contiguous
        atomicAdd(&kvt[bh * 4096 + idx], red[idx]);
    }
    if (tid < 64) {
        float s = 0.f;
        #pragma unroll
        for (int m = 0; m < 32; m++)
            s += ksl[((tid >> 3) + m * 8) * 8 + (tid & 7)];
        atomicAdd(&ksum[bh * 64 + tid], s);
    }
}

// one-shot split-precision pack of kvt fp32 -> f16 hi/lo (attn B-operands)
__global__ void kv_pack(const float* __restrict__ kvt,
                        f16* __restrict__ kvhi, f16* __restrict__ kvlo)
{
    int idx = blockIdx.x * 256 + threadIdx.x;   // grid 128 -> 32768 x4 elems
    float4 v = *(const float4*)&kvt[idx * 4];
    f16x4 hi, lo;
    hi[0] = (f16)v.x; lo[0] = (f16)(v.x - (float)hi[0]);
    hi[1] = (f16)v.y; lo[1] = (f16)(v.y - (float)hi[1]);
    hi[2] = (f16)v.z; lo[2] = (f16)(v.z - (float)hi[2]);
    hi[3] = (f16)v.w; lo[3] = (f16)(v.w - (float)hi[3]);
    *(f16x4*)&kvhi[idx * 4] = hi;
    *(f16x4*)&kvlo[idx * 4] = lo;
}

// attn via MFMA: out[n][e] = (q[n][:] @ kv[:][e]) / (q[n][:].ksum + eps).
// B-fragments (split-precision hi/lo KV) read DIRECTLY from global (16B
// contiguous, L2-resident, reused by 64 blocks per bh). A-frags straight
// from global Q. No LDS, no barriers. z in-register via 2x shfl_xor.
__global__ __launch_bounds__(256, 4)
void attn_kernel(const f16* __restrict__ q, const f16* __restrict__ kvhi,
                 const f16* __restrict__ kvlo, const float* __restrict__ ksum,
                 f16* __restrict__ attnh)
{
    int bh = blockIdx.x;
    int b = bh >> 3, h = bh & 7;
    int rc = blockIdx.y;
    int tid = threadIdx.x;
    const int lane = tid & 63;
    const int wave = tid >> 6;
    const int l15 = lane & 15;
    const int l4  = lane >> 4;

    // B fragments from global, reused for all 4 row tiles
    f16x8 bhi[2][4], blo[2][4];
    #pragma unroll
    for (int s = 0; s < 2; s++)
        #pragma unroll
        for (int nt = 0; nt < 4; nt++) {
            int e = nt * 16 + l15;
            size_t gb = (size_t)bh * 4096 + e * 64 + s * 32 + l4 * 8;
            bhi[s][nt] = *(const f16x8*)&kvhi[gb];
            blo[s][nt] = *(const f16x8*)&kvlo[gb];
        }
    // per-lane ksum slice: d = s*32 + l4*8 + j
    float ksA[2][8];
    #pragma unroll
    for (int s = 0; s < 2; s++)
        #pragma unroll
        for (int j = 0; j < 8; j++)
            ksA[s][j] = ksum[bh * 64 + s * 32 + l4 * 8 + j];

    const size_t qbase = ((size_t)b * NTOK + rc * 256 + wave * 64) * CDIM + (size_t)h * HD;

    #pragma unroll
    for (int mt = 0; mt < 4; mt++) {
        f16x8 af[2];
        #pragma unroll
        for (int s = 0; s < 2; s++)
            af[s] = *(const f16x8*)&q[qbase + (size_t)(mt * 16 + l15) * CDIM + s * 32 + l4 * 8];

        // z for row mt*16 + l15
        float zp = 0.f;
        #pragma unroll
        for (int s = 0; s < 2; s++)
            #pragma unroll
            for (int j = 0; j < 8; j++)
                zp += (float)af[s][j] * ksA[s][j];
        zp += __shfl_xor(zp, 16, 64);
        zp += __shfl_xor(zp, 32, 64);
        float zinv = 1.f / (zp + 1e-6f);

        f32x4 acc[4];
        #pragma unroll
        for (int nt = 0; nt < 4; nt++) acc[nt] = (f32x4){0.f, 0.f, 0.f, 0.f};
        #pragma unroll
        for (int s = 0; s < 2; s++)
            #pragma unroll
            for (int nt = 0; nt < 4; nt++) {
                acc[nt] = __builtin_amdgcn_mfma_f32_16x16x32_f16(af[s], bhi[s][nt], acc[nt], 0, 0, 0);
                acc[nt] = __builtin_amdgcn_mfma_f32_16x16x32_f16(af[s], blo[s][nt], acc[nt], 0, 0, 0);
            }

        #pragma unroll
        for (int r = 0; r < 4; r++) {
            float zr = __shfl(zinv, l4 * 4 + r, 64);   // z from lane l15==row
            size_t orow = qbase + (size_t)(mt * 16 + l4 * 4 + r) * CDIM;
            #pragma unroll
            for (int nt = 0; nt < 4; nt++)
                attnh[orow + nt * 16 + l15] = (f16)(acc[nt][r] * zr);
        }
    }
}

extern "C" void kernel_launch(void* const* d_in, const int* in_sizes, int n_in,
                              void* d_out, int out_size, void* d_ws, size_t ws_size,
                              hipStream_t stream)
{
    const float* x      = (const float*)d_in[0];
    const float* w_qkv  = (const float*)d_in[1];
    const float* b_qkv  = (const float*)d_in[2];
    const float* w_proj = (const float*)d_in[3];
    const float* b_proj = (const float*)d_in[4];
    float* out = (float*)d_out;
    char*  ws  = (char*)d_ws;

    const size_t NCB = (size_t)M_ROWS * CDIM * sizeof(f16);   // 64 MiB
    f16*   xh   = (f16*)(ws);
    f16*   qh   = (f16*)(ws + NCB * 1);
    f16*   kh   = (f16*)(ws + NCB * 2);
    f16*   vh   = (f16*)(ws + NCB * 3);          // reused as attn_h after kv_kernel
    f16*   wqt  = (f16*)(ws + NCB * 4);
    f16*   wpt  = (f16*)(ws + NCB * 4 + (1536 * 512) * sizeof(f16));
    float* tab  = (float*)(ws + NCB * 4 + (1536 * 512 + 512 * 512) * sizeof(f16));
    float* kvp  = tab + 8192;
    float* ksum = kvp + 32 * 4096;
    f16*   kvhi = (f16*)(ksum + 32 * 64);
    f16*   kvlo = kvhi + 32 * 4096;

    hipMemsetAsync(kvp, 0, (32 * 4096 + 32 * 64) * sizeof(float), stream);
    rope_tables<<<1, 256, 0, stream>>>(tab);
    convert_x_f16<<<M_ROWS * CDIM / 8 / 256, 256, 0, stream>>>(x, xh);
    convert_wT<1><<<1536 * 512 / 256, 256, 0, stream>>>(w_qkv, wqt, 1536);
    convert_wT<1><<<512 * 512 / 256, 256, 0, stream>>>(w_proj, wpt, 512);

    gemm_f16<1><<<6144, 256, 0, stream>>>(xh, wqt, b_qkv,
                                          nullptr, qh, kh, vh, tab, 12);
    kv_kernel<<<dim3(32, 16), 256, 0, stream>>>(kh, vh, kvp, ksum);
    kv_pack<<<128, 256, 0, stream>>>(kvp, kvhi, kvlo);
    attn_kernel<<<dim3(32, 64), 256, 0, stream>>>(qh, kvhi, kvlo, ksum, vh);
    gemm_f16<0><<<2048, 256, 0, stream>>>(vh, wpt, b_proj,
                                          out, nullptr, nullptr, nullptr, nullptr, 4);
}

// Round 6
// 537.618 us; speedup vs baseline: 1.3400x; 1.0005x over previous
//
#include <hip/hip_runtime.h>
#include <math.h>

#define BATCH 4
#define NTOK  16384
#define CDIM  512
#define NH    8
#define HD    64
#define M_ROWS (BATCH*NTOK)
#define KDIM  512

typedef _Float16 f16;
typedef _Float16 f16x8 __attribute__((ext_vector_type(8)));
typedef _Float16 f16x4 __attribute__((ext_vector_type(4)));
typedef _Float16 f16x2 __attribute__((ext_vector_type(2)));
typedef float    f32x4 __attribute__((ext_vector_type(4)));

__device__ __forceinline__ void load_lds16(const void* g, void* l) {
    __builtin_amdgcn_global_load_lds(
        (const __attribute__((address_space(1))) void*)g,
        (__attribute__((address_space(3))) void*)l, 16, 0, 0);
}

// ---------------- fused prep: convert_x + both weight transposes + rope -----
// One launch; block ranges run concurrently so the 192MB convert_x stream
// hides the (formerly serial) weight transpose and rope-table work.
//   blocks [0, 16384)          : x fp32 -> f16 (8 elems/thread)
//   blocks [16384, 16384+1024) : w_qkv / w_proj transpose via 32x33 LDS tile,
//                                coalesced read AND write, with the column
//                                PERM (pos<16 -> 2p, else 2(p-16)+1) that the
//                                GEMM epilogues rely on.
//   blocks [+1024, +1040)      : rope table, f32 powf+sincosf (angle <= 127
//                                rad; err ~4e-5 << f16 resolution).
// tab = float2[2][128][16]: {cos,sin}, isy{x:t=tok&127, y:t=tok>>7}, 16 freqs.
__global__ __launch_bounds__(256)
void prep(const float* __restrict__ x, f16* __restrict__ xh,
          const float* __restrict__ wq, f16* __restrict__ wqt,
          const float* __restrict__ wp, f16* __restrict__ wpt,
          float* __restrict__ tab)
{
    const int bid = blockIdx.x;
    const int tid = threadIdx.x;
    __shared__ float lds[32][33];

    if (bid < 16384) {
        int i = bid * 256 + tid;
        float4 a = *(const float4*)&x[(size_t)i * 8];
        float4 b = *(const float4*)&x[(size_t)i * 8 + 4];
        f16x8 o;
        o[0]=(f16)a.x; o[1]=(f16)a.y; o[2]=(f16)a.z; o[3]=(f16)a.w;
        o[4]=(f16)b.x; o[5]=(f16)b.y; o[6]=(f16)b.z; o[7]=(f16)b.w;
        *(f16x8*)&xh[(size_t)i * 8] = o;
    } else if (bid < 16384 + 1024) {
        int tb = bid - 16384;
        const float* src; f16* dst; int N;
        if (tb < 768) { src = wq; dst = wqt; N = 1536; }
        else          { tb -= 768; src = wp; dst = wpt; N = 512; }
        int kt  = tb & 15;        // k-tile (K=512 -> 16 tiles)
        int ntl = tb >> 4;        // n-tile
        int tx = tid & 31, ty = tid >> 5;
        #pragma unroll
        for (int i = 0; i < 4; i++)
            lds[ty + 8 * i][tx] = src[(size_t)(kt * 32 + ty + 8 * i) * N + ntl * 32 + tx];
        __syncthreads();
        #pragma unroll
        for (int i = 0; i < 4; i++) {
            int p  = ty + 8 * i;
            int tc = (p < 16) ? (2 * p) : (2 * (p - 16) + 1);
            dst[(size_t)(ntl * 32 + p) * 512 + kt * 32 + tx] = (f16)lds[tx][tc];
        }
    } else {
        int idx = (bid - (16384 + 1024)) * 256 + tid;   // 0..4095 pairs
        int t   = (idx >> 4) & 127;
        int fi  = idx & 15;
        float freq = powf(10.f, -(float)fi / 16.f);
        float s, c;
        sincosf((float)t * freq, &s, &c);
        tab[idx * 2]     = c;
        tab[idx * 2 + 1] = s;
    }
}

// ---------------- fp16 MFMA GEMM, 128x128 tile, BK=64 per barrier ------------
// Proven structure (R3/R5: ~143us, MfmaUtil 32%, conflicts 0): single-buffered
// LDS [128][64] f16, T2 XOR-swizzle (chunk ^= row&7) applied on both the
// pre-swizzled global source and the ds_read side (rule 21). 32 KB LDS ->
// ~3 blocks/CU whose cross-block overlap hides the stage drain (explicit
// dbuf regressed: R2). XCD-swizzled 1D grid for L2 locality.
// Both MODE paths use column-PERMUTED weights.
template<int MODE>
__global__ __launch_bounds__(256, 2)
void gemm_f16(const f16* __restrict__ A, const f16* __restrict__ Bt,
              const float* __restrict__ bias,
              float* __restrict__ Co,
              f16* __restrict__ qd, f16* __restrict__ kd, f16* __restrict__ vd,
              const float* __restrict__ tab, int ncol_tiles)
{
    __shared__ f16 As[128 * 64];
    __shared__ f16 Bs[128 * 64];
    const int tid  = threadIdx.x;
    const int lane = tid & 63;
    const int wave = tid >> 6;
    const int wy = wave >> 1, wx = wave & 1;

    const int bid = blockIdx.x;
    const int xcd = bid & 7;
    const int idx = bid >> 3;
    const int ct  = idx % ncol_tiles;
    const int rt  = (idx / ncol_tiles) * 8 + xcd;
    const int row0 = rt * 128;
    const int col0 = ct * 128;

    const int l15 = lane & 15;
    const int l4  = lane >> 4;

    f32x4 acc[4][4];
    #pragma unroll
    for (int mt = 0; mt < 4; mt++)
        #pragma unroll
        for (int nt = 0; nt < 4; nt++)
            acc[mt][nt] = (f32x4){0.f, 0.f, 0.f, 0.f};

    const int pbase = wave * 256;   // 16B-chunk base for this wave (4 issues x 64)

    for (int k0 = 0; k0 < KDIM; k0 += 64) {
        #pragma unroll
        for (int i = 0; i < 4; i++) {
            int p  = pbase + i * 64 + lane;   // chunk id 0..1023
            int m  = p >> 3;                  // tile row 0..127
            int jp = p & 7;                   // physical 16B chunk within row
            int j  = jp ^ (m & 7);            // logical k-chunk to fetch (swizzle)
            load_lds16(&A [(size_t)(row0 + m) * KDIM + k0 + j * 8],
                       &As[(pbase + i * 64) * 8]);
            load_lds16(&Bt[(size_t)(col0 + m) * KDIM + k0 + j * 8],
                       &Bs[(pbase + i * 64) * 8]);
        }
        __syncthreads();

        #pragma unroll
        for (int s = 0; s < 2; s++) {
            f16x8 af[4], bf[4];
            #pragma unroll
            for (int t = 0; t < 4; t++) {
                int ra = wy * 64 + t * 16 + l15;
                int rb = wx * 64 + t * 16 + l15;
                int ca = ((s << 2) | l4) ^ (ra & 7);
                int cb = ((s << 2) | l4) ^ (rb & 7);
                af[t] = *(const f16x8*)&As[ra * 64 + ca * 8];
                bf[t] = *(const f16x8*)&Bs[rb * 64 + cb * 8];
            }
            #pragma unroll
            for (int mt = 0; mt < 4; mt++)
                #pragma unroll
                for (int nt = 0; nt < 4; nt++)
                    acc[mt][nt] = __builtin_amdgcn_mfma_f32_16x16x32_f16(af[mt], bf[nt], acc[mt][nt], 0, 0, 0);
        }
        __syncthreads();
    }

    if (MODE == 0) {
        // Permuted-column direct-store epilogue: lane l15 owns true cols
        // (2*l15, 2*l15+1); float2 stores. No LDS, no barriers.
        #pragma unroll
        for (int q = 0; q < 2; q++) {
            int B32 = (col0 + wx * 64 + q * 32) >> 5;
            int t0c = B32 * 32 + 2 * l15;
            float bv0 = bias[t0c];
            float bv1 = bias[t0c + 1];
            #pragma unroll
            for (int mt = 0; mt < 4; mt++)
                #pragma unroll
                for (int r = 0; r < 4; r++) {
                    int row = row0 + wy * 64 + mt * 16 + l4 * 4 + r;
                    float2 o2;
                    o2.x = acc[mt][2 * q][r]     + bv0;
                    o2.y = acc[mt][2 * q + 1][r] + bv1;
                    *(float2*)&Co[(size_t)row * CDIM + t0c] = o2;
                }
        }
    } else {
        // Permuted-column epilogue with fused RoPE+ELU for Q/K, plain for V.
        const int which = col0 >> 9;
        f16* dst = (which == 0) ? qd : (which == 1) ? kd : vd;
        const float2* tab2 = (const float2*)tab;
        #pragma unroll
        for (int q = 0; q < 2; q++) {
            int B32  = (col0 + wx * 64 + q * 32) >> 5;   // 32-col block id
            int t0   = B32 * 32 + 2 * l15;               // true col (even)
            int c512 = t0 & 511;
            float bv0 = bias[t0];
            float bv1 = bias[t0 + 1];
            int isy  = B32 & 1;                          // x-half / y-half of head
            const float2* ct = tab2 + isy * 2048 + l15;  // [isy][t][fi=l15]
            if (which == 2) {
                #pragma unroll
                for (int mt = 0; mt < 4; mt++)
                    #pragma unroll
                    for (int r = 0; r < 4; r++) {
                        int row = row0 + wy * 64 + mt * 16 + l4 * 4 + r;
                        f16x2 pk;
                        pk[0] = (f16)(acc[mt][2 * q][r]     + bv0);
                        pk[1] = (f16)(acc[mt][2 * q + 1][r] + bv1);
                        *(f16x2*)&dst[(size_t)row * CDIM + c512] = pk;
                    }
            } else {
                #pragma unroll
                for (int mt = 0; mt < 4; mt++)
                    #pragma unroll
                    for (int r = 0; r < 4; r++) {
                        int row = row0 + wy * 64 + mt * 16 + l4 * 4 + r;
                        int tok = row & (NTOK - 1);
                        int t   = isy ? (tok >> 7) : (tok & 127);
                        float2 cs = ct[t * 16];
                        float xr = acc[mt][2 * q][r]     + bv0;
                        float xi = acc[mt][2 * q + 1][r] + bv1;
                        float o_r = xr * cs.x - xi * cs.y;
                        float o_i = xr * cs.y + xi * cs.x;
                        o_r = (o_r > 0.f) ? o_r + 1.f : __expf(o_r);
                        o_i = (o_i > 0.f) ? o_i + 1.f : __expf(o_i);
                        f16x2 pk; pk[0] = (f16)o_r; pk[1] = (f16)o_i;
                        *(f16x2*)&dst[(size_t)row * CDIM + c512] = pk;
                    }
            }
        }
    }
}

// kv_kernel: 8x8 register tiles; 64B LDS per 64 FMA. Wave partials merged
// once per block through LDS, then 4096 atomics. ksum accumulated per-thread
// during staging (fixed o-slice since 256 % 8 == 0), reduced at block end.
__global__ __launch_bounds__(256, 4)
void kv_kernel(const f16* __restrict__ kk, const f16* __restrict__ vv,
               float* __restrict__ kvt, float* __restrict__ ksum)
{
    int bh = blockIdx.x;
    int b = bh >> 3, h = bh & 7;
    int t0 = blockIdx.y * 1024;
    __shared__ float ks[64][68];
    __shared__ float vs[64][68];
    int tid = threadIdx.x;
    const int wave = tid >> 6;
    const int lane = tid & 63;
    const int ly = lane >> 3;
    const int lx = lane & 7;
    const int o  = (tid & 7) * 8;     // fixed dim slice this thread stages

    float acc[8][8];
    float ksacc[8];
    #pragma unroll
    for (int r = 0; r < 8; r++) { ksacc[r] = 0.f;
        #pragma unroll
        for (int j = 0; j < 8; j++) acc[r][j] = 0.f; }

    const size_t rowbase = (size_t)b * NTOK;
    for (int tt = t0; tt < t0 + 1024; tt += 64) {
        #pragma unroll
        for (int i = 0; i < 2; i++) {
            int idx = tid + i * 256;
            int tok = idx >> 3;
            size_t g = (rowbase + tt + tok) * CDIM + h * HD + o;
            f16x8 k8 = *(const f16x8*)&kk[g];
            f16x8 v8 = *(const f16x8*)&vv[g];
            float4 klo = {(float)k8[0], (float)k8[1], (float)k8[2], (float)k8[3]};
            float4 khi = {(float)k8[4], (float)k8[5], (float)k8[6], (float)k8[7]};
            float4 vlo = {(float)v8[0], (float)v8[1], (float)v8[2], (float)v8[3]};
            float4 vhi = {(float)v8[4], (float)v8[5], (float)v8[6], (float)v8[7]};
            *(float4*)&ks[tok][o]     = klo;
            *(float4*)&ks[tok][o + 4] = khi;
            *(float4*)&vs[tok][o]     = vlo;
            *(float4*)&vs[tok][o + 4] = vhi;
            ksacc[0] += klo.x; ksacc[1] += klo.y; ksacc[2] += klo.z; ksacc[3] += klo.w;
            ksacc[4] += khi.x; ksacc[5] += khi.y; ksacc[6] += khi.z; ksacc[7] += khi.w;
        }
        __syncthreads();
        #pragma unroll
        for (int t5 = 0; t5 < 16; t5++) {
            int t = wave * 16 + t5;
            float4 ka0 = *(const float4*)&ks[t][ly * 8];
            float4 ka1 = *(const float4*)&ks[t][ly * 8 + 4];
            float4 va0 = *(const float4*)&vs[t][lx * 8];
            float4 va1 = *(const float4*)&vs[t][lx * 8 + 4];
            float ka[8] = {ka0.x, ka0.y, ka0.z, ka0.w, ka1.x, ka1.y, ka1.z, ka1.w};
            float va[8] = {va0.x, va0.y, va0.z, va0.w, va1.x, va1.y, va1.z, va1.w};
            #pragma unroll
            for (int r = 0; r < 8; r++)
                #pragma unroll
                for (int j = 0; j < 8; j++) acc[r][j] += ka[r] * va[j];
        }
        __syncthreads();
    }

    // ksum partials -> LDS (vs region is free now)
    float* ksl = &vs[0][0];
    {
        float4 a = {ksacc[0], ksacc[1], ksacc[2], ksacc[3]};
        float4 c = {ksacc[4], ksacc[5], ksacc[6], ksacc[7]};
        *(float4*)&ksl[tid * 8]     = a;
        *(float4*)&ksl[tid * 8 + 4] = c;
    }
    // merge 4 wave partials into red[e][d] (transposed), ks region reused
    float* red = &ks[0][0];
    #pragma unroll
    for (int w = 0; w < 4; w++) {
        if (wave == w) {
            #pragma unroll
            for (int j = 0; j < 8; j++) {
                int base = (lx * 8 + j) * 64 + ly * 8;
                float4 lo = {acc[0][j], acc[1][j], acc[2][j], acc[3][j]};
                float4 hi = {acc[4][j], acc[5][j], acc[6][j], acc[7][j]};
                if (w == 0) {
                    *(float4*)&red[base]     = lo;
                    *(float4*)&red[base + 4] = hi;
                } else {
                    float4 p0 = *(const float4*)&red[base];
                    float4 p1 = *(const float4*)&red[base + 4];
                    p0.x += lo.x; p0.y += lo.y; p0.z += lo.z; p0.w += lo.w;
                    p1.x += hi.x; p1.y += hi.y; p1.z += hi.z; p1.w += hi.w;
                    *(float4*)&red[base]     = p0;
                    *(float4*)&red[base + 4] = p1;
                }
            }
        }
        __syncthreads();
    }
    #pragma unroll
    for (int i = 0; i < 16; i++) {
        int idx = tid + i * 256;          // [e][d] order, contiguous
        atomicAdd(&kvt[bh * 4096 + idx], red[idx]);
    }
    if (tid < 64) {
        float s = 0.f;
        #pragma unroll
        for (int m = 0; m < 32; m++)
            s += ksl[((tid >> 3) + m * 8) * 8 + (tid & 7)];
        atomicAdd(&ksum[bh * 64 + tid], s);
    }
}

// one-shot split-precision pack of kvt fp32 -> f16 hi/lo (attn B-operands)
__global__ void kv_pack(const float* __restrict__ kvt,
                        f16* __restrict__ kvhi, f16* __restrict__ kvlo)
{
    int idx = blockIdx.x * 256 + threadIdx.x;   // grid 128 -> 32768 x4 elems
    float4 v = *(const float4*)&kvt[idx * 4];
    f16x4 hi, lo;
    hi[0] = (f16)v.x; lo[0] = (f16)(v.x - (float)hi[0]);
    hi[1] = (f16)v.y; lo[1] = (f16)(v.y - (float)hi[1]);
    hi[2] = (f16)v.z; lo[2] = (f16)(v.z - (float)hi[2]);
    hi[3] = (f16)v.w; lo[3] = (f16)(v.w - (float)hi[3]);
    *(f16x4*)&kvhi[idx * 4] = hi;
    *(f16x4*)&kvlo[idx * 4] = lo;
}

// attn via MFMA: out[n][e] = (q[n][:] @ kv[:][e]) / (q[n][:].ksum + eps).
// B-fragments (split-precision hi/lo KV) read DIRECTLY from global (16B
// contiguous, L2-resident, reused by 64 blocks per bh). A-frags straight
// from global Q. No LDS, no barriers. z in-register via 2x shfl_xor.
__global__ __launch_bounds__(256, 4)
void attn_kernel(const f16* __restrict__ q, const f16* __restrict__ kvhi,
                 const f16* __restrict__ kvlo, const float* __restrict__ ksum,
                 f16* __restrict__ attnh)
{
    int bh = blockIdx.x;
    int b = bh >> 3, h = bh & 7;
    int rc = blockIdx.y;
    int tid = threadIdx.x;
    const int lane = tid & 63;
    const int wave = tid >> 6;
    const int l15 = lane & 15;
    const int l4  = lane >> 4;

    // B fragments from global, reused for all 4 row tiles
    f16x8 bhi[2][4], blo[2][4];
    #pragma unroll
    for (int s = 0; s < 2; s++)
        #pragma unroll
        for (int nt = 0; nt < 4; nt++) {
            int e = nt * 16 + l15;
            size_t gb = (size_t)bh * 4096 + e * 64 + s * 32 + l4 * 8;
            bhi[s][nt] = *(const f16x8*)&kvhi[gb];
            blo[s][nt] = *(const f16x8*)&kvlo[gb];
        }
    // per-lane ksum slice: d = s*32 + l4*8 + j
    float ksA[2][8];
    #pragma unroll
    for (int s = 0; s < 2; s++)
        #pragma unroll
        for (int j = 0; j < 8; j++)
            ksA[s][j] = ksum[bh * 64 + s * 32 + l4 * 8 + j];

    const size_t qbase = ((size_t)b * NTOK + rc * 256 + wave * 64) * CDIM + (size_t)h * HD;

    #pragma unroll
    for (int mt = 0; mt < 4; mt++) {
        f16x8 af[2];
        #pragma unroll
        for (int s = 0; s < 2; s++)
            af[s] = *(const f16x8*)&q[qbase + (size_t)(mt * 16 + l15) * CDIM + s * 32 + l4 * 8];

        // z for row mt*16 + l15
        float zp = 0.f;
        #pragma unroll
        for (int s = 0; s < 2; s++)
            #pragma unroll
            for (int j = 0; j < 8; j++)
                zp += (float)af[s][j] * ksA[s][j];
        zp += __shfl_xor(zp, 16, 64);
        zp += __shfl_xor(zp, 32, 64);
        float zinv = 1.f / (zp + 1e-6f);

        f32x4 acc[4];
        #pragma unroll
        for (int nt = 0; nt < 4; nt++) acc[nt] = (f32x4){0.f, 0.f, 0.f, 0.f};
        #pragma unroll
        for (int s = 0; s < 2; s++)
            #pragma unroll
            for (int nt = 0; nt < 4; nt++) {
                acc[nt] = __builtin_amdgcn_mfma_f32_16x16x32_f16(af[s], bhi[s][nt], acc[nt], 0, 0, 0);
                acc[nt] = __builtin_amdgcn_mfma_f32_16x16x32_f16(af[s], blo[s][nt], acc[nt], 0, 0, 0);
            }

        #pragma unroll
        for (int r = 0; r < 4; r++) {
            float zr = __shfl(zinv, l4 * 4 + r, 64);   // z from lane l15==row
            size_t orow = qbase + (size_t)(mt * 16 + l4 * 4 + r) * CDIM;
            #pragma unroll
            for (int nt = 0; nt < 4; nt++)
                attnh[orow + nt * 16 + l15] = (f16)(acc[nt][r] * zr);
        }
    }
}

extern "C" void kernel_launch(void* const* d_in, const int* in_sizes, int n_in,
                              void* d_out, int out_size, void* d_ws, size_t ws_size,
                              hipStream_t stream)
{
    const float* x      = (const float*)d_in[0];
    const float* w_qkv  = (const float*)d_in[1];
    const float* b_qkv  = (const float*)d_in[2];
    const float* w_proj = (const float*)d_in[3];
    const float* b_proj = (const float*)d_in[4];
    float* out = (float*)d_out;
    char*  ws  = (char*)d_ws;

    const size_t NCB = (size_t)M_ROWS * CDIM * sizeof(f16);   // 64 MiB
    f16*   xh   = (f16*)(ws);
    f16*   qh   = (f16*)(ws + NCB * 1);
    f16*   kh   = (f16*)(ws + NCB * 2);
    f16*   vh   = (f16*)(ws + NCB * 3);          // reused as attn_h after kv_kernel
    f16*   wqt  = (f16*)(ws + NCB * 4);
    f16*   wpt  = (f16*)(ws + NCB * 4 + (1536 * 512) * sizeof(f16));
    float* tab  = (float*)(ws + NCB * 4 + (1536 * 512 + 512 * 512) * sizeof(f16));
    float* kvp  = tab + 8192;
    float* ksum = kvp + 32 * 4096;
    f16*   kvhi = (f16*)(ksum + 32 * 64);
    f16*   kvlo = kvhi + 32 * 4096;

    hipMemsetAsync(kvp, 0, (32 * 4096 + 32 * 64) * sizeof(float), stream);
    prep<<<16384 + 1024 + 16, 256, 0, stream>>>(x, xh, w_qkv, wqt, w_proj, wpt, tab);

    gemm_f16<1><<<6144, 256, 0, stream>>>(xh, wqt, b_qkv,
                                          nullptr, qh, kh, vh, tab, 12);
    kv_kernel<<<dim3(32, 16), 256, 0, stream>>>(kh, vh, kvp, ksum);
    kv_pack<<<128, 256, 0, stream>>>(kvp, kvhi, kvlo);
    attn_kernel<<<dim3(32, 64), 256, 0, stream>>>(qh, kvhi, kvlo, ksum, vh);
    gemm_f16<0><<<2048, 256, 0, stream>>>(vh, wpt, b_proj,
                                          out, nullptr, nullptr, nullptr, nullptr, 4);
}